// Round 1
// baseline (326.145 us; speedup 1.0000x reference)
//
#include <hip/hip_runtime.h>

#define NREL 8192
#define RD   256

typedef float f32x4 __attribute__((ext_vector_type(4)));
typedef short s16x8 __attribute__((ext_vector_type(8)));
typedef unsigned int  u32;
typedef unsigned short u16;

__device__ __forceinline__ u16 f2bf(float f) {
    u32 b = __float_as_uint(f);
    return (u16)((b + 0x7FFFu + ((b >> 16) & 1u)) >> 16);   // RNE, f >= 0 here
}

// ---------------- K1: u_left/u_right = W_common^T @ w_{l,r}; init rmax key ---
__global__ __launch_bounds__(256) void k_prep(
    const float* __restrict__ W, const float* __restrict__ wl,
    const float* __restrict__ wr, float* __restrict__ ul,
    float* __restrict__ ur, u32* __restrict__ rmaxk)
{
    __shared__ float sL[256], sR[256];
    const int t = threadIdx.x;
    const int d = blockIdx.x * 16 + (t & 15);
    float aL = 0.f, aR = 0.f;
    for (int h = (t >> 4); h < 256; h += 16) {
        float w = W[h * 512 + d];
        aL += w * wl[h];
        aR += w * wr[h];
    }
    sL[t] = aL; sR[t] = aR;
    __syncthreads();
    if (t < 16) {
        float xL = 0.f, xR = 0.f;
        for (int g = 0; g < 16; g++) { xL += sL[g * 16 + t]; xR += sR[g * 16 + t]; }
        ul[blockIdx.x * 16 + t] = xL;
        ur[blockIdx.x * 16 + t] = xR;
    }
    if (blockIdx.x == 0 && t == 0) *rmaxk = 0u;   // key of -inf
}

// ---------------- K2: left/right rows + global max(right) via uint-keyed atomicMax
__global__ __launch_bounds__(256) void k_lr(
    const float* __restrict__ ctx, const float* __restrict__ ul,
    const float* __restrict__ ur, const float* __restrict__ bl,
    const float* __restrict__ br, float* __restrict__ left,
    float* __restrict__ right, u32* __restrict__ rmaxk)
{
    const int lane = threadIdx.x & 63;
    const int row  = blockIdx.x * 4 + (threadIdx.x >> 6);
    const f32x4* cv = (const f32x4*)(ctx + (size_t)row * 512);
    const f32x4* uv = (const f32x4*)ul;
    const f32x4* vv = (const f32x4*)ur;
    f32x4 c0 = cv[lane], c1 = cv[lane + 64];
    f32x4 u0 = uv[lane], u1 = uv[lane + 64];
    f32x4 v0 = vv[lane], v1 = vv[lane + 64];
    float dl = c0.x*u0.x + c0.y*u0.y + c0.z*u0.z + c0.w*u0.w
             + c1.x*u1.x + c1.y*u1.y + c1.z*u1.z + c1.w*u1.w;
    float dr = c0.x*v0.x + c0.y*v0.y + c0.z*v0.z + c0.w*v0.w
             + c1.x*v1.x + c1.y*v1.y + c1.z*v1.z + c1.w*v1.w;
    #pragma unroll
    for (int o = 1; o < 64; o <<= 1) { dl += __shfl_xor(dl, o); dr += __shfl_xor(dr, o); }
    if (lane == 0) {
        float L = dl + bl[0], Rv = dr + br[0];
        left[row]  = L;
        right[row] = Rv;
        u32 b = __float_as_uint(Rv);
        u32 key = ((int)b >= 0) ? (b | 0x80000000u) : ~b;   // monotone float->uint
        atomicMax(rmaxk, key);
    }
}

// ---------------- Krt: Rt[n][k] = bf16(relation[k][n])  (256 x 8192 bf16) ----
__global__ __launch_bounds__(256) void k_rt(const float* __restrict__ R,
                                            u16* __restrict__ Rt)
{
    const int n = blockIdx.x;
    const int t = threadIdx.x;
    for (int j0 = t * 8; j0 < NREL; j0 += 2048) {
        u32 pk[4];
        #pragma unroll
        for (int q = 0; q < 4; q++) {
            u16 e0 = f2bf(R[(size_t)(j0 + 2 * q) * RD + n]);
            u16 e1 = f2bf(R[(size_t)(j0 + 2 * q + 1) * RD + n]);
            pk[q] = (u32)e0 | ((u32)e1 << 16);
        }
        u32* dst = (u32*)(Rt + (size_t)n * NREL + j0);
        dst[0] = pk[0]; dst[1] = pk[1]; dst[2] = pk[2]; dst[3] = pk[3];
    }
}

// ---------------- K3: fused masked-softmax attention ------------------------
// block = 64 rows x 256 cols, 8 waves (wave w owns cols [w*32, w*32+32))
// K-loop step 64; P tile (64x64 bf16) in LDS, XOR-swizzled ((row&7)<<4 bytes)
template<int USE_RT>
__global__ __launch_bounds__(512) void k_attn(
    const float* __restrict__ adj, const u16* __restrict__ Rt,
    const float* __restrict__ rel, const float* __restrict__ left,
    const float* __restrict__ right, const u32* __restrict__ rmaxk,
    float* __restrict__ out)
{
    __shared__ u32   Pl[64 * 32];   // 64x64 bf16 swizzled = 8 KB
    __shared__ float dnm[64];

    const int tid  = threadIdx.x;
    const int lane = tid & 63;
    const int wv   = tid >> 6;          // 0..7
    const int l15  = lane & 15;
    const int lq   = lane >> 4;         // 0..3
    const int rowblk = blockIdx.x * 64;

    const int pr = tid >> 4;            // 0..31  (P-gen row)
    const int pq = tid & 15;            // 0..15  (P-gen k-quad: k = pq*4..pq*4+3)

    const float lft0 = left[rowblk + pr];
    const float lft1 = left[rowblk + pr + 32];
    const u32 kbits = *rmaxk;
    const float rmax = __uint_as_float((kbits & 0x80000000u) ? (kbits ^ 0x80000000u)
                                                             : ~kbits);
    float z;
    z = lft0 + rmax; const float m0 = fmaxf(z, 0.2f * z);   // lrelu upper bound row pr
    z = lft1 + rmax; const float m1 = fmaxf(z, 0.2f * z);

    f32x4 acc[4][2];
    #pragma unroll
    for (int i = 0; i < 4; i++) { acc[i][0] = (f32x4)0.f; acc[i][1] = (f32x4)0.f; }
    float dp0 = 0.f, dp1 = 0.f;

    const f32x4* adjv = (const f32x4*)adj;
    const f32x4* rv4  = (const f32x4*)right;
    const size_t arow0 = (size_t)(rowblk + pr) * 2048;
    const size_t arow1 = (size_t)(rowblk + pr + 32) * 2048;
    const int n0 = wv * 32 + l15;

    // swizzled LDS write indices (uint units); rows r and r+32 share (r&7)
    const u32 widx0 = (u32)pr * 32 + (((u32)pq * 2) ^ (((u32)pr & 7) << 2));
    const u32 widx1 = widx0 + 1024;

    // ---- prefetch tile jb=0
    f32x4 a0 = adjv[arow0 + pq];
    f32x4 a1 = adjv[arow1 + pq];
    f32x4 rv = rv4[pq];
    s16x8 bcur[2][2];
    #pragma unroll
    for (int kk = 0; kk < 2; kk++)
        #pragma unroll
        for (int ct = 0; ct < 2; ct++) {
            if (USE_RT) {
                bcur[kk][ct] = *(const s16x8*)(Rt + (size_t)(n0 + ct * 16) * NREL
                                               + kk * 32 + lq * 8);
            } else {
                const float* rp = rel + (size_t)(kk * 32 + lq * 8) * RD + (n0 + ct * 16);
                s16x8 b;
                #pragma unroll
                for (int e = 0; e < 8; e++) b[e] = (short)f2bf(rp[(size_t)e * RD]);
                bcur[kk][ct] = b;
            }
        }

    for (int jb = 0; jb < NREL; jb += 64) {
        const int jn = (jb + 64) & (NREL - 1);
        // ---- prefetch next tile (independent; compiler issues early)
        f32x4 na0 = adjv[arow0 + (jn >> 2) + pq];
        f32x4 na1 = adjv[arow1 + (jn >> 2) + pq];
        f32x4 nrv = rv4[(jn >> 2) + pq];
        s16x8 bnxt[2][2];
        #pragma unroll
        for (int kk = 0; kk < 2; kk++)
            #pragma unroll
            for (int ct = 0; ct < 2; ct++) {
                if (USE_RT) {
                    bnxt[kk][ct] = *(const s16x8*)(Rt + (size_t)(n0 + ct * 16) * NREL
                                                   + jn + kk * 32 + lq * 8);
                } else {
                    const float* rp = rel + (size_t)(jn + kk * 32 + lq * 8) * RD
                                          + (n0 + ct * 16);
                    s16x8 b;
                    #pragma unroll
                    for (int e = 0; e < 8; e++) b[e] = (short)f2bf(rp[(size_t)e * RD]);
                    bnxt[kk][ct] = b;
                }
            }

        // ---- P-gen: p = adj * exp(lrelu(left+right) - m)   (exact softmax shift)
        float pa[4], pb[4];
        #pragma unroll
        for (int e = 0; e < 4; e++) {
            const float r = rv[e];
            float z0 = lft0 + r; float s0 = fmaxf(z0, 0.2f * z0);
            pa[e] = a0[e] * __expf(s0 - m0);
            float z1 = lft1 + r; float s1 = fmaxf(z1, 0.2f * z1);
            pb[e] = a1[e] * __expf(s1 - m1);
        }
        dp0 += pa[0] + pa[1] + pa[2] + pa[3];
        dp1 += pb[0] + pb[1] + pb[2] + pb[3];
        Pl[widx0]     = (u32)f2bf(pa[0]) | ((u32)f2bf(pa[1]) << 16);
        Pl[widx0 + 1] = (u32)f2bf(pa[2]) | ((u32)f2bf(pa[3]) << 16);
        Pl[widx1]     = (u32)f2bf(pb[0]) | ((u32)f2bf(pb[1]) << 16);
        Pl[widx1 + 1] = (u32)f2bf(pb[2]) | ((u32)f2bf(pb[3]) << 16);

        __syncthreads();

        // ---- MFMA: X += P @ R   (A: LDS swizzled, B: registers from global Rt)
        #pragma unroll
        for (int kk = 0; kk < 2; kk++) {
            s16x8 af[4];
            #pragma unroll
            for (int rt = 0; rt < 4; rt++) {
                const int row = rt * 16 + l15;
                const int us  = row * 64 + ((kk * 32 + lq * 8) ^ ((row & 7) << 3));
                af[rt] = *(const s16x8*)((const u16*)Pl + us);
            }
            #pragma unroll
            for (int ct = 0; ct < 2; ct++)
                #pragma unroll
                for (int rt = 0; rt < 4; rt++)
                    acc[rt][ct] = __builtin_amdgcn_mfma_f32_16x16x32_bf16(
                        af[rt], bcur[kk][ct], acc[rt][ct], 0, 0, 0);
        }
        __syncthreads();

        a0 = na0; a1 = na1; rv = nrv;
        #pragma unroll
        for (int kk = 0; kk < 2; kk++)
            #pragma unroll
            for (int ct = 0; ct < 2; ct++) bcur[kk][ct] = bnxt[kk][ct];
    }

    // ---- denominators: reduce per-thread partials across the 16 k-lanes
    #pragma unroll
    for (int o = 1; o < 16; o <<= 1) { dp0 += __shfl_xor(dp0, o); dp1 += __shfl_xor(dp1, o); }
    if (pq == 0) { dnm[pr] = dp0; dnm[pr + 32] = dp1; }
    __syncthreads();

    // ---- epilogue: x = relu(acc / denom)
    #pragma unroll
    for (int rt = 0; rt < 4; rt++)
        #pragma unroll
        for (int ct = 0; ct < 2; ct++)
            #pragma unroll
            for (int r = 0; r < 4; r++) {
                const int row = rt * 16 + lq * 4 + r;
                float v = acc[rt][ct][r] / dnm[row];
                v = fmaxf(v, 0.f);
                out[(size_t)(rowblk + row) * RD + (wv * 32 + ct * 16 + l15)] = v;
            }
}

extern "C" void kernel_launch(void* const* d_in, const int* in_sizes, int n_in,
                              void* d_out, int out_size, void* d_ws, size_t ws_size,
                              hipStream_t stream)
{
    const float* relation = (const float*)d_in[0];
    const float* context  = (const float*)d_in[1];
    const float* adj      = (const float*)d_in[2];
    const float* W        = (const float*)d_in[3];
    const float* wl       = (const float*)d_in[4];
    const float* bl       = (const float*)d_in[5];
    const float* wr       = (const float*)d_in[6];
    const float* br       = (const float*)d_in[7];
    float* out = (float*)d_out;

    float* wsf   = (float*)d_ws;
    float* ul    = wsf;
    float* ur    = wsf + 512;
    float* left  = wsf + 1024;
    float* right = wsf + 1024 + 8192;
    u32*   rmaxk = (u32*)(wsf + 1024 + 16384);
    u16*   Rt    = (u16*)((char*)d_ws + 81920);
    const size_t need = 81920 + (size_t)RD * NREL * 2;
    const bool use_rt = ws_size >= need;

    hipLaunchKernelGGL(k_prep, dim3(32), dim3(256), 0, stream, W, wl, wr, ul, ur, rmaxk);
    hipLaunchKernelGGL(k_lr, dim3(2048), dim3(256), 0, stream,
                       context, ul, ur, bl, br, left, right, rmaxk);
    if (use_rt) {
        hipLaunchKernelGGL(k_rt, dim3(256), dim3(256), 0, stream, relation, Rt);
        hipLaunchKernelGGL(k_attn<1>, dim3(128), dim3(512), 0, stream,
                           adj, Rt, relation, left, right, rmaxk, out);
    } else {
        hipLaunchKernelGGL(k_attn<0>, dim3(128), dim3(512), 0, stream,
                           adj, (const u16*)nullptr, relation, left, right, rmaxk, out);
    }
}

// Round 2
// 241.980 us; speedup vs baseline: 1.3478x; 1.3478x over previous
//
#include <hip/hip_runtime.h>

#define NREL 8192
#define RD   256

typedef float f32x4 __attribute__((ext_vector_type(4)));
typedef short s16x8 __attribute__((ext_vector_type(8)));
typedef unsigned int  u32;
typedef unsigned short u16;

__device__ __forceinline__ u16 f2bf(float f) {
    u32 b = __float_as_uint(f);
    return (u16)((b + 0x7FFFu + ((b >> 16) & 1u)) >> 16);   // RNE, f >= 0 here
}

// ---------------- K1: u_left/u_right = W_common^T @ w_{l,r}; init rmax key ---
__global__ __launch_bounds__(256) void k_prep(
    const float* __restrict__ W, const float* __restrict__ wl,
    const float* __restrict__ wr, float* __restrict__ ul,
    float* __restrict__ ur, u32* __restrict__ rmaxk)
{
    __shared__ float sL[256], sR[256];
    const int t = threadIdx.x;
    const int d = blockIdx.x * 16 + (t & 15);
    float aL = 0.f, aR = 0.f;
    for (int h = (t >> 4); h < 256; h += 16) {
        float w = W[h * 512 + d];
        aL += w * wl[h];
        aR += w * wr[h];
    }
    sL[t] = aL; sR[t] = aR;
    __syncthreads();
    if (t < 16) {
        float xL = 0.f, xR = 0.f;
        for (int g = 0; g < 16; g++) { xL += sL[g * 16 + t]; xR += sR[g * 16 + t]; }
        ul[blockIdx.x * 16 + t] = xL;
        ur[blockIdx.x * 16 + t] = xR;
    }
    if (blockIdx.x == 0 && t == 0) *rmaxk = 0u;   // key of -inf
}

// ---------------- K2: left/right rows + global max(right) via uint-keyed atomicMax
__global__ __launch_bounds__(256) void k_lr(
    const float* __restrict__ ctx, const float* __restrict__ ul,
    const float* __restrict__ ur, const float* __restrict__ bl,
    const float* __restrict__ br, float* __restrict__ left,
    float* __restrict__ right, u32* __restrict__ rmaxk)
{
    const int lane = threadIdx.x & 63;
    const int row  = blockIdx.x * 4 + (threadIdx.x >> 6);
    const f32x4* cv = (const f32x4*)(ctx + (size_t)row * 512);
    const f32x4* uv = (const f32x4*)ul;
    const f32x4* vv = (const f32x4*)ur;
    f32x4 c0 = cv[lane], c1 = cv[lane + 64];
    f32x4 u0 = uv[lane], u1 = uv[lane + 64];
    f32x4 v0 = vv[lane], v1 = vv[lane + 64];
    float dl = c0.x*u0.x + c0.y*u0.y + c0.z*u0.z + c0.w*u0.w
             + c1.x*u1.x + c1.y*u1.y + c1.z*u1.z + c1.w*u1.w;
    float dr = c0.x*v0.x + c0.y*v0.y + c0.z*v0.z + c0.w*v0.w
             + c1.x*v1.x + c1.y*v1.y + c1.z*v1.z + c1.w*v1.w;
    #pragma unroll
    for (int o = 1; o < 64; o <<= 1) { dl += __shfl_xor(dl, o); dr += __shfl_xor(dr, o); }
    if (lane == 0) {
        float L = dl + bl[0], Rv = dr + br[0];
        left[row]  = L;
        right[row] = Rv;
        u32 b = __float_as_uint(Rv);
        u32 key = ((int)b >= 0) ? (b | 0x80000000u) : ~b;   // monotone float->uint
        atomicMax(rmaxk, key);
    }
}

// ---------------- Krt: Rt[n][k] = bf16(relation[k][n])  (256 x 8192 bf16) ----
__global__ __launch_bounds__(256) void k_rt(const float* __restrict__ R,
                                            u16* __restrict__ Rt)
{
    const int n = blockIdx.x;
    const int t = threadIdx.x;
    for (int j0 = t * 8; j0 < NREL; j0 += 2048) {
        u32 pk[4];
        #pragma unroll
        for (int q = 0; q < 4; q++) {
            u16 e0 = f2bf(R[(size_t)(j0 + 2 * q) * RD + n]);
            u16 e1 = f2bf(R[(size_t)(j0 + 2 * q + 1) * RD + n]);
            pk[q] = (u32)e0 | ((u32)e1 << 16);
        }
        u32* dst = (u32*)(Rt + (size_t)n * NREL + j0);
        dst[0] = pk[0]; dst[1] = pk[1]; dst[2] = pk[2]; dst[3] = pk[3];
    }
}

// ---------------- K3: fused masked-softmax attention (K-split by S) ---------
// block = 64 rows x 256 cols x (NREL/S) j-cols; 8 waves; s = bid % S (XCD affinity)
// S==1: divide+relu+write out directly. S>1: write partial num/den to ws.
template<int USE_RT, int S>
__global__ __launch_bounds__(512) void k_attn(
    const float* __restrict__ adj, const u16* __restrict__ Rt,
    const float* __restrict__ rel, const float* __restrict__ left,
    const float* __restrict__ right, const u32* __restrict__ rmaxk,
    float* __restrict__ outp, float* __restrict__ pden)
{
    __shared__ u32   Pl[64 * 32];   // 64x64 bf16 swizzled = 8 KB
    __shared__ float dnm[64];

    const int tid  = threadIdx.x;
    const int lane = tid & 63;
    const int wv   = tid >> 6;          // 0..7
    const int l15  = lane & 15;
    const int lq   = lane >> 4;         // 0..3
    const int s      = (S > 1) ? (int)(blockIdx.x % (unsigned)S) : 0;
    const int rowblk = (int)(blockIdx.x / (unsigned)S) * 64;
    const int jbeg = s * (NREL / S);
    const int jend = jbeg + (NREL / S);

    const int pr = tid >> 4;            // 0..31  (P-gen row)
    const int pq = tid & 15;            // 0..15  (P-gen k-quad)

    const float lft0 = left[rowblk + pr];
    const float lft1 = left[rowblk + pr + 32];
    const u32 kbits = *rmaxk;
    const float rmax = __uint_as_float((kbits & 0x80000000u) ? (kbits ^ 0x80000000u)
                                                             : ~kbits);
    float z;
    z = lft0 + rmax; const float m0 = fmaxf(z, 0.2f * z);   // lrelu upper bound row pr
    z = lft1 + rmax; const float m1 = fmaxf(z, 0.2f * z);

    f32x4 acc[4][2];
    #pragma unroll
    for (int i = 0; i < 4; i++) { acc[i][0] = (f32x4)0.f; acc[i][1] = (f32x4)0.f; }
    float dp0 = 0.f, dp1 = 0.f;

    const f32x4* adjv = (const f32x4*)adj;
    const f32x4* rv4  = (const f32x4*)right;
    const size_t arow0 = (size_t)(rowblk + pr) * 2048;
    const size_t arow1 = (size_t)(rowblk + pr + 32) * 2048;
    const int n0 = wv * 32 + l15;

    // swizzled LDS write indices (uint units); rows r and r+32 share (r&7)
    const u32 widx0 = (u32)pr * 32 + (((u32)pq * 2) ^ (((u32)pr & 7) << 2));
    const u32 widx1 = widx0 + 1024;

    // ---- prefetch first tile
    f32x4 a0 = adjv[arow0 + (jbeg >> 2) + pq];
    f32x4 a1 = adjv[arow1 + (jbeg >> 2) + pq];
    f32x4 rv = rv4[(jbeg >> 2) + pq];
    s16x8 bcur[2][2];
    #pragma unroll
    for (int kk = 0; kk < 2; kk++)
        #pragma unroll
        for (int ct = 0; ct < 2; ct++) {
            if (USE_RT) {
                bcur[kk][ct] = *(const s16x8*)(Rt + (size_t)(n0 + ct * 16) * NREL
                                               + jbeg + kk * 32 + lq * 8);
            } else {
                const float* rp = rel + (size_t)(jbeg + kk * 32 + lq * 8) * RD + (n0 + ct * 16);
                s16x8 b;
                #pragma unroll
                for (int e = 0; e < 8; e++) b[e] = (short)f2bf(rp[(size_t)e * RD]);
                bcur[kk][ct] = b;
            }
        }

    for (int jb = jbeg; jb < jend; jb += 64) {
        const int jn = (jb + 64 < jend) ? (jb + 64) : jbeg;
        // ---- prefetch next tile (independent; compiler issues early)
        f32x4 na0 = adjv[arow0 + (jn >> 2) + pq];
        f32x4 na1 = adjv[arow1 + (jn >> 2) + pq];
        f32x4 nrv = rv4[(jn >> 2) + pq];
        s16x8 bnxt[2][2];
        #pragma unroll
        for (int kk = 0; kk < 2; kk++)
            #pragma unroll
            for (int ct = 0; ct < 2; ct++) {
                if (USE_RT) {
                    bnxt[kk][ct] = *(const s16x8*)(Rt + (size_t)(n0 + ct * 16) * NREL
                                                   + jn + kk * 32 + lq * 8);
                } else {
                    const float* rp = rel + (size_t)(jn + kk * 32 + lq * 8) * RD
                                          + (n0 + ct * 16);
                    s16x8 b;
                    #pragma unroll
                    for (int e = 0; e < 8; e++) b[e] = (short)f2bf(rp[(size_t)e * RD]);
                    bnxt[kk][ct] = b;
                }
            }

        // ---- P-gen: p = adj * exp(lrelu(left+right) - m)   (exact softmax shift)
        float pa[4], pb[4];
        #pragma unroll
        for (int e = 0; e < 4; e++) {
            const float r = rv[e];
            float z0 = lft0 + r; float s0 = fmaxf(z0, 0.2f * z0);
            pa[e] = a0[e] * __expf(s0 - m0);
            float z1 = lft1 + r; float s1 = fmaxf(z1, 0.2f * z1);
            pb[e] = a1[e] * __expf(s1 - m1);
        }
        dp0 += pa[0] + pa[1] + pa[2] + pa[3];
        dp1 += pb[0] + pb[1] + pb[2] + pb[3];
        Pl[widx0]     = (u32)f2bf(pa[0]) | ((u32)f2bf(pa[1]) << 16);
        Pl[widx0 + 1] = (u32)f2bf(pa[2]) | ((u32)f2bf(pa[3]) << 16);
        Pl[widx1]     = (u32)f2bf(pb[0]) | ((u32)f2bf(pb[1]) << 16);
        Pl[widx1 + 1] = (u32)f2bf(pb[2]) | ((u32)f2bf(pb[3]) << 16);

        __syncthreads();

        // ---- MFMA: X += P @ R   (A: LDS swizzled, B: registers from global Rt)
        #pragma unroll
        for (int kk = 0; kk < 2; kk++) {
            s16x8 af[4];
            #pragma unroll
            for (int rt = 0; rt < 4; rt++) {
                const int row = rt * 16 + l15;
                const int us  = row * 64 + ((kk * 32 + lq * 8) ^ ((row & 7) << 3));
                af[rt] = *(const s16x8*)((const u16*)Pl + us);
            }
            #pragma unroll
            for (int ct = 0; ct < 2; ct++)
                #pragma unroll
                for (int rt = 0; rt < 4; rt++)
                    acc[rt][ct] = __builtin_amdgcn_mfma_f32_16x16x32_bf16(
                        af[rt], bcur[kk][ct], acc[rt][ct], 0, 0, 0);
        }
        __syncthreads();

        a0 = na0; a1 = na1; rv = nrv;
        #pragma unroll
        for (int kk = 0; kk < 2; kk++)
            #pragma unroll
            for (int ct = 0; ct < 2; ct++) bcur[kk][ct] = bnxt[kk][ct];
    }

    // ---- denominators: reduce per-thread partials across the 16 k-lanes
    #pragma unroll
    for (int o = 1; o < 16; o <<= 1) { dp0 += __shfl_xor(dp0, o); dp1 += __shfl_xor(dp1, o); }

    if (S > 1) {
        if (pq == 0) {
            pden[(size_t)s * NREL + rowblk + pr]      = dp0;
            pden[(size_t)s * NREL + rowblk + pr + 32] = dp1;
        }
        float* pn = outp + (size_t)s * NREL * RD;
        #pragma unroll
        for (int rt = 0; rt < 4; rt++)
            #pragma unroll
            for (int ct = 0; ct < 2; ct++)
                #pragma unroll
                for (int r = 0; r < 4; r++) {
                    const int row = rt * 16 + lq * 4 + r;
                    pn[(size_t)(rowblk + row) * RD + (wv * 32 + ct * 16 + l15)] =
                        acc[rt][ct][r];
                }
    } else {
        if (pq == 0) { dnm[pr] = dp0; dnm[pr + 32] = dp1; }
        __syncthreads();
        #pragma unroll
        for (int rt = 0; rt < 4; rt++)
            #pragma unroll
            for (int ct = 0; ct < 2; ct++)
                #pragma unroll
                for (int r = 0; r < 4; r++) {
                    const int row = rt * 16 + lq * 4 + r;
                    float v = acc[rt][ct][r] / dnm[row];
                    v = fmaxf(v, 0.f);
                    outp[(size_t)(rowblk + row) * RD + (wv * 32 + ct * 16 + l15)] = v;
                }
    }
}

// ---------------- K4: reduce partials: out = relu(sum num / sum den) --------
template<int S>
__global__ __launch_bounds__(256) void k_red(
    const float* __restrict__ pnum, const float* __restrict__ pden,
    float* __restrict__ out)
{
    const int idx = blockIdx.x * 256 + threadIdx.x;   // f32x4 index
    const int row = idx >> 6;                          // 64 f32x4 per row
    float den = 0.f;
    #pragma unroll
    for (int s = 0; s < S; s++) den += pden[(size_t)s * NREL + row];
    const f32x4* pn4 = (const f32x4*)pnum;
    f32x4 a = (f32x4)0.f;
    #pragma unroll
    for (int s = 0; s < S; s++) a += pn4[(size_t)s * (NREL * RD / 4) + idx];
    f32x4 r;
    r.x = fmaxf(a.x / den, 0.f);
    r.y = fmaxf(a.y / den, 0.f);
    r.z = fmaxf(a.z / den, 0.f);
    r.w = fmaxf(a.w / den, 0.f);
    ((f32x4*)out)[idx] = r;
}

extern "C" void kernel_launch(void* const* d_in, const int* in_sizes, int n_in,
                              void* d_out, int out_size, void* d_ws, size_t ws_size,
                              hipStream_t stream)
{
    const float* relation = (const float*)d_in[0];
    const float* context  = (const float*)d_in[1];
    const float* adj      = (const float*)d_in[2];
    const float* W        = (const float*)d_in[3];
    const float* wl       = (const float*)d_in[4];
    const float* bl       = (const float*)d_in[5];
    const float* wr       = (const float*)d_in[6];
    const float* br       = (const float*)d_in[7];
    float* out = (float*)d_out;

    float* wsf   = (float*)d_ws;
    float* ul    = wsf;
    float* ur    = wsf + 512;
    float* left  = wsf + 1024;
    float* right = wsf + 1024 + 8192;
    u32*   rmaxk = (u32*)(wsf + 1024 + 16384);
    const size_t hdr  = 81920;
    const size_t rt_b = (size_t)NREL * RD * 2;          // 4 MB
    u16*   Rt   = (u16*)((char*)d_ws + hdr);
    float* pnum = (float*)((char*)d_ws + hdr + rt_b);

    hipLaunchKernelGGL(k_prep, dim3(32), dim3(256), 0, stream, W, wl, wr, ul, ur, rmaxk);
    hipLaunchKernelGGL(k_lr, dim3(2048), dim3(256), 0, stream,
                       context, ul, ur, bl, br, left, right, rmaxk);

    auto need = [&](int S) {
        return hdr + rt_b + (size_t)S * NREL * RD * 4 + (size_t)S * NREL * 4;
    };

    if (ws_size >= need(8)) {
        float* pden = pnum + (size_t)8 * NREL * RD;
        hipLaunchKernelGGL(k_rt, dim3(256), dim3(256), 0, stream, relation, Rt);
        hipLaunchKernelGGL((k_attn<1, 8>), dim3(128 * 8), dim3(512), 0, stream,
                           adj, Rt, relation, left, right, rmaxk, pnum, pden);
        hipLaunchKernelGGL((k_red<8>), dim3(2048), dim3(256), 0, stream,
                           pnum, pden, out);
    } else if (ws_size >= need(4)) {
        float* pden = pnum + (size_t)4 * NREL * RD;
        hipLaunchKernelGGL(k_rt, dim3(256), dim3(256), 0, stream, relation, Rt);
        hipLaunchKernelGGL((k_attn<1, 4>), dim3(128 * 4), dim3(512), 0, stream,
                           adj, Rt, relation, left, right, rmaxk, pnum, pden);
        hipLaunchKernelGGL((k_red<4>), dim3(2048), dim3(256), 0, stream,
                           pnum, pden, out);
    } else if (ws_size >= need(2)) {
        float* pden = pnum + (size_t)2 * NREL * RD;
        hipLaunchKernelGGL(k_rt, dim3(256), dim3(256), 0, stream, relation, Rt);
        hipLaunchKernelGGL((k_attn<1, 2>), dim3(128 * 2), dim3(512), 0, stream,
                           adj, Rt, relation, left, right, rmaxk, pnum, pden);
        hipLaunchKernelGGL((k_red<2>), dim3(2048), dim3(256), 0, stream,
                           pnum, pden, out);
    } else if (ws_size >= hdr + rt_b) {
        hipLaunchKernelGGL(k_rt, dim3(256), dim3(256), 0, stream, relation, Rt);
        hipLaunchKernelGGL((k_attn<1, 1>), dim3(128), dim3(512), 0, stream,
                           adj, Rt, relation, left, right, rmaxk, out, (float*)nullptr);
    } else {
        hipLaunchKernelGGL((k_attn<0, 1>), dim3(128), dim3(512), 0, stream,
                           adj, (const u16*)nullptr, relation, left, right, rmaxk,
                           out, (float*)nullptr);
    }
}